// Round 6
// baseline (4833.302 us; speedup 1.0000x reference)
//
#include <hip/hip_runtime.h>

#define HDIM 128
#define TDIM 2048
#define BDIM 256
#define CHUNK 16
#define NT 512
#define XGP 20   // fp32 dword pitch per gate row in xg_s

typedef _Float16 half2_t __attribute__((ext_vector_type(2)));
typedef _Float16 half8_t __attribute__((ext_vector_type(8)));
typedef float f32x4 __attribute__((ext_vector_type(4)));
struct H2x4 { half2_t h[4]; };

__device__ __forceinline__ float fdot2(half2_t a, half2_t b, float c) {
    return __builtin_amdgcn_fdot2(a, b, c, false);
}
__device__ __forceinline__ f32x4 mfma16(half8_t a, half8_t b, f32x4 c) {
    return __builtin_amdgcn_mfma_f32_16x16x32_f16(a, b, c, 0, 0, 0);
}

// Workgroup barrier WITHOUT the compiler's vmcnt(0) drain: LDS visibility only.
// Safe here because no cross-thread data flows through global memory between
// these barriers (gbuf chunk reads/writes are >=2 chunks apart; inter-layer
// handoff uses real __syncthreads()).
__device__ __forceinline__ void fast_barrier() {
    asm volatile("s_waitcnt lgkmcnt(0)\n\ts_barrier" ::: "memory");
}

// Butterfly sum across the DPP quad: all 4 lanes get the total.
__device__ __forceinline__ float quad_sum(float v) {
    int i = __builtin_bit_cast(int, v);
    int a = __builtin_amdgcn_update_dpp(0, i, 0xB1, 0xF, 0xF, true);
    v += __builtin_bit_cast(float, a);
    i = __builtin_bit_cast(int, v);
    int b = __builtin_amdgcn_update_dpp(0, i, 0x4E, 0xF, 0xF, true);
    v += __builtin_bit_cast(float, b);
    return v;
}

__device__ __forceinline__ float sigm_f(float x) { return 1.0f / (1.0f + __expf(-x)); }
__device__ __forceinline__ float tanh_f(float x) { return 1.0f - 2.0f / (1.0f + __expf(2.0f * x)); }

// 4 gates' 32-element partial dots from four half8 input fragments
__device__ __forceinline__ void dot4g(half8_t A, half8_t B, half8_t C, half8_t D,
                                      const half2_t (&w)[4][16], float (&out)[4]) {
    H2x4 a = __builtin_bit_cast(H2x4, A);
    H2x4 b = __builtin_bit_cast(H2x4, B);
    H2x4 c = __builtin_bit_cast(H2x4, C);
    H2x4 d = __builtin_bit_cast(H2x4, D);
#pragma unroll
    for (int q = 0; q < 4; ++q) {
        float s0 = 0.f, s1 = 0.f;
#pragma unroll
        for (int j = 0; j < 4; ++j) {
            s0 = fdot2(a.h[j], w[q][j],      s0);
            s0 = fdot2(b.h[j], w[q][4 + j],  s0);
            s1 = fdot2(c.h[j], w[q][8 + j],  s1);
            s1 = fdot2(d.h[j], w[q][12 + j], s1);
        }
        out[q] = s0 + s1;
    }
}

__device__ __forceinline__ void load_whh(const _Float16* wp, int u, int p,
                                         half2_t (&w)[4][16]) {
#pragma unroll
    for (int q = 0; q < 4; ++q) {
        const int row = q * HDIM + u;
        const half8_t* wr = (const half8_t*)(wp + (size_t)row * HDIM + p * 32);
        H2x4 u0 = __builtin_bit_cast(H2x4, wr[0]);
        H2x4 u1 = __builtin_bit_cast(H2x4, wr[1]);
        H2x4 u2 = __builtin_bit_cast(H2x4, wr[2]);
        H2x4 u3 = __builtin_bit_cast(H2x4, wr[3]);
#pragma unroll
        for (int j = 0; j < 4; ++j) {
            w[q][j] = u0.h[j];      w[q][4 + j] = u1.h[j];
            w[q][8 + j] = u2.h[j];  w[q][12 + j] = u3.h[j];
        }
    }
}

// One-time fp32 -> fp16 weight conversion. Segments of 65536: [Whh0,Wih1,Whh1,Wih2,Whh2]
__global__ __launch_bounds__(256)
void convert_w(const float* __restrict__ Whh0, const float* __restrict__ Wih1,
               const float* __restrict__ Whh1, const float* __restrict__ Wih2,
               const float* __restrict__ Whh2, _Float16* __restrict__ dst) {
    int i = blockIdx.x * 256 + threadIdx.x;
    int seg = i >> 16, off = i & 65535;
    const float* s = (seg == 0) ? Whh0 : (seg == 1) ? Wih1 : (seg == 2) ? Whh1
                   : (seg == 3) ? Wih2 : Whh2;
    dst[i] = (_Float16)s[off];
}

__global__ __launch_bounds__(NT, 2)
void lstm3_kernel(const float* __restrict__ x,   const float* __restrict__ Wih0,
                  const float* __restrict__ bih0, const float* __restrict__ bhh0,
                  const float* __restrict__ bih1, const float* __restrict__ bhh1,
                  const float* __restrict__ bih2, const float* __restrict__ bhh2,
                  const float* __restrict__ fc1w, const float* __restrict__ fc1b,
                  const float* __restrict__ fc2w, const float* __restrict__ fc2b,
                  float* __restrict__ out,
                  _Float16* __restrict__ gbuf, const _Float16* __restrict__ wbuf)
{
    // rolling 16-step h window: row t&15 holds h(t). Doubles as output staging.
    __shared__ __align__(16) _Float16 hwin_s[CHUNK][HDIM];
    __shared__ __align__(16) _Float16 xin_s[2][CHUNK][HDIM];
    __shared__ __align__(16) float xg_s[2][512 * XGP];
    __shared__ __align__(16) float z_s[64];

    const int tid = threadIdx.x;
    const int u = tid >> 2;     // hidden unit
    const int p = tid & 3;      // K-quarter / DPP-quad lane
    const int ln = tid & 63;
    const int wv = tid >> 6;
    const int b = blockIdx.x;

    half2_t whh[4][16];

    // ================= layer 0 (in_dim = 1) =================
    {
        float bsum[4], w0[4];
        load_whh(wbuf, u, p, whh);
#pragma unroll
        for (int q = 0; q < 4; ++q) {
            const int row = q * HDIM + u;
            bsum[q] = bih0[row] + bhh0[row];
            w0[q] = Wih0[row];
        }
        if (tid < HDIM) hwin_s[CHUNK - 1][tid] = (_Float16)0.f;  // h(-1) = 0
        float c = 0.f;
        float4 xp[4];
        {
            const float4* xq = (const float4*)(x + (size_t)b * TDIM);
#pragma unroll
            for (int i = 0; i < 4; ++i) xp[i] = xq[i];
        }

#pragma unroll 1
        for (int t0 = 0; t0 < TDIM; t0 += CHUNK) {
            float xv[CHUNK];
#pragma unroll
            for (int i = 0; i < 4; ++i) {
                xv[4 * i] = xp[i].x; xv[4 * i + 1] = xp[i].y;
                xv[4 * i + 2] = xp[i].z; xv[4 * i + 3] = xp[i].w;
            }
            int tn = (t0 + CHUNK < TDIM) ? (t0 + CHUNK) : t0;
            const float4* xq = (const float4*)(x + (size_t)b * TDIM + tn);
#pragma unroll
            for (int i = 0; i < 4; ++i) xp[i] = xq[i];

#pragma unroll
            for (int tt = 0; tt < CHUNK; ++tt) {
                fast_barrier();
                const int t = t0 + tt;
                const half8_t* hvp = (const half8_t*)&hwin_s[(t + CHUNK - 1) & 15][p * 32];
                float P[4];
                dot4g(hvp[0], hvp[1], hvp[2], hvp[3], whh, P);
#pragma unroll
                for (int q = 0; q < 4; ++q) P[q] = quad_sum(P[q]);
                float ig = sigm_f(P[0] + xv[tt] * w0[0] + bsum[0]);
                float fg = sigm_f(P[1] + xv[tt] * w0[1] + bsum[1]);
                float gg = tanh_f(P[2] + xv[tt] * w0[2] + bsum[2]);
                float og = sigm_f(P[3] + xv[tt] * w0[3] + bsum[3]);
                c = fg * c + ig * gg;
                if (p == 0) hwin_s[t & 15][u] = (_Float16)(og * tanh_f(c));
            }
            // flush the whole window (chunk rows are contiguous in gbuf)
            fast_barrier();
            int2 v = ((const int2*)&hwin_s[0][0])[tid];
            ((int2*)(gbuf + ((size_t)b * TDIM + t0) * HDIM))[tid] = v;
        }
    }

    // ================= layers 1,2 (MFMA projection) =================
#pragma unroll 1
    for (int layer = 1; layer < 3; ++layer) {
        const _Float16* whh_p = wbuf + (size_t)((layer == 1) ? 2 : 4) * 65536;
        const _Float16* wih_p = wbuf + (size_t)((layer == 1) ? 1 : 3) * 65536;
        const float* bih = (layer == 1) ? bih1 : bih2;
        const float* bhh = (layer == 1) ? bhh1 : bhh2;

        float bsum[4];
        load_whh(whh_p, u, p, whh);
#pragma unroll
        for (int q = 0; q < 4; ++q) bsum[q] = bih[q * HDIM + u] + bhh[q * HDIM + u];

        half8_t bfr[4][4];
#pragma unroll
        for (int tau = 0; tau < 4; ++tau) {
            const int g = (wv * 4 + tau) * 16 + (ln & 15);
#pragma unroll
            for (int kk = 0; kk < 4; ++kk)
                bfr[tau][kk] = *(const half8_t*)(wih_p + (size_t)g * HDIM + kk * 32 + (ln >> 4) * 8);
        }

        __syncthreads();   // REAL barrier: drains prev layer's gbuf stores before reads
        if (tid < HDIM) hwin_s[CHUNK - 1][tid] = (_Float16)0.f;
        float c = 0.f;

        // ---- prologue: proj chunk 0 -> xg_s[0], prefetch chunk 1 ----
        int2 stage = ((const int2*)(gbuf + (size_t)b * TDIM * HDIM))[tid];
        ((int2*)&xin_s[0][0][0])[tid] = stage;
        __syncthreads();
        {
            const int m = ln & 15, kb = (ln >> 4) * 8;
            half8_t A0 = *(const half8_t*)&xin_s[0][m][kb];
            half8_t A1 = *(const half8_t*)&xin_s[0][m][32 + kb];
            half8_t A2 = *(const half8_t*)&xin_s[0][m][64 + kb];
            half8_t A3 = *(const half8_t*)&xin_s[0][m][96 + kb];
#pragma unroll
            for (int tau = 0; tau < 4; ++tau) {
                f32x4 a = {0.f, 0.f, 0.f, 0.f};
                a = mfma16(A0, bfr[tau][0], a);
                a = mfma16(A1, bfr[tau][1], a);
                a = mfma16(A2, bfr[tau][2], a);
                a = mfma16(A3, bfr[tau][3], a);
                const int g = (wv * 4 + tau) * 16 + (ln & 15);
                *(f32x4*)&xg_s[0][g * XGP + (ln >> 4) * 4] = a;
            }
        }
        stage = ((const int2*)(gbuf + ((size_t)b * TDIM + CHUNK) * HDIM))[tid];

        f32x4 pacc[4];
#pragma unroll 1
        for (int t0 = 0; t0 < TDIM; t0 += CHUNK) {
            const int ci = t0 >> 4, rbuf = ci & 1, cb = rbuf ^ 1;
            ((int2*)&xin_s[cb][0][0])[tid] = stage;
            int tn = (t0 + 2 * CHUNK < TDIM) ? (t0 + 2 * CHUNK) : t0;
            stage = ((const int2*)(gbuf + ((size_t)b * TDIM + tn) * HDIM))[tid];

            float2 xgv[4];
#pragma unroll
            for (int tt = 0; tt < CHUNK; ++tt) {
                fast_barrier();
                const int t = t0 + tt;
                const half8_t* hvp = (const half8_t*)&hwin_s[(t + CHUNK - 1) & 15][p * 32];
                half8_t hA = hvp[0], hB = hvp[1], hC = hvp[2], hD = hvp[3];

                if (tt == 0) {
                    const int m = ln & 15, kb = (ln >> 4) * 8;
                    half8_t A0 = *(const half8_t*)&xin_s[cb][m][kb];
                    half8_t A1 = *(const half8_t*)&xin_s[cb][m][32 + kb];
                    half8_t A2 = *(const half8_t*)&xin_s[cb][m][64 + kb];
                    half8_t A3 = *(const half8_t*)&xin_s[cb][m][96 + kb];
#pragma unroll
                    for (int tau = 0; tau < 4; ++tau) {
                        f32x4 a = {0.f, 0.f, 0.f, 0.f};
                        a = mfma16(A0, bfr[tau][0], a);
                        a = mfma16(A1, bfr[tau][1], a);
                        a = mfma16(A2, bfr[tau][2], a);
                        a = mfma16(A3, bfr[tau][3], a);
                        pacc[tau] = a;
                    }
                }
                if ((tt & 1) == 0) {
#pragma unroll
                    for (int q = 0; q < 4; ++q)
                        xgv[q] = *(const float2*)&xg_s[rbuf][(q * HDIM + u) * XGP + tt];
                }

                float P[4];
                dot4g(hA, hB, hC, hD, whh, P);
#pragma unroll
                for (int q = 0; q < 4; ++q) P[q] = quad_sum(P[q]);

                float x0 = (tt & 1) ? xgv[0].y : xgv[0].x;
                float x1 = (tt & 1) ? xgv[1].y : xgv[1].x;
                float x2 = (tt & 1) ? xgv[2].y : xgv[2].x;
                float x3 = (tt & 1) ? xgv[3].y : xgv[3].x;
                float ig = sigm_f(P[0] + x0 + bsum[0]);
                float fg = sigm_f(P[1] + x1 + bsum[1]);
                float gg = tanh_f(P[2] + x2 + bsum[2]);
                float og = sigm_f(P[3] + x3 + bsum[3]);
                c = fg * c + ig * gg;
                if (p == 0) hwin_s[t & 15][u] = (_Float16)(og * tanh_f(c));

                if (tt == CHUNK - 1) {
#pragma unroll
                    for (int tau = 0; tau < 4; ++tau) {
                        const int g = (wv * 4 + tau) * 16 + (ln & 15);
                        *(f32x4*)&xg_s[cb][g * XGP + (ln >> 4) * 4] = pacc[tau];
                    }
                }
            }
            if (layer == 1) {
                fast_barrier();
                int2 v = ((const int2*)&hwin_s[0][0])[tid];
                ((int2*)(gbuf + ((size_t)b * TDIM + t0) * HDIM))[tid] = v;
            }
        }
    }

    // ---- FC head: final h (t=2047) is hwin_s[15] ----
    __syncthreads();
    if (tid < 64) {
        const float* w = fc1w + tid * HDIM;
        float s = fc1b[tid];
#pragma unroll
        for (int k = 0; k < HDIM; ++k) s += w[k] * (float)hwin_s[CHUNK - 1][k];
        z_s[tid] = fmaxf(s, 0.0f);
    }
    __syncthreads();
    if (tid < 5) {
        const float* w = fc2w + tid * 64;
        float s = fc2b[tid];
#pragma unroll
        for (int k = 0; k < 64; ++k) s += w[k] * z_s[k];
        out[b * 5 + tid] = s;
    }
}

extern "C" void kernel_launch(void* const* d_in, const int* in_sizes, int n_in,
                              void* d_out, int out_size, void* d_ws, size_t ws_size,
                              hipStream_t stream) {
    (void)in_sizes; (void)n_in; (void)out_size; (void)ws_size;
    const float* x    = (const float*)d_in[0];
    const float* Wih0 = (const float*)d_in[1];
    const float* Whh0 = (const float*)d_in[2];
    const float* bih0 = (const float*)d_in[3];
    const float* bhh0 = (const float*)d_in[4];
    const float* Wih1 = (const float*)d_in[5];
    const float* Whh1 = (const float*)d_in[6];
    const float* bih1 = (const float*)d_in[7];
    const float* bhh1 = (const float*)d_in[8];
    const float* Wih2 = (const float*)d_in[9];
    const float* Whh2 = (const float*)d_in[10];
    const float* bih2 = (const float*)d_in[11];
    const float* bhh2 = (const float*)d_in[12];
    const float* fc1w = (const float*)d_in[13];
    const float* fc1b = (const float*)d_in[14];
    const float* fc2w = (const float*)d_in[15];
    const float* fc2b = (const float*)d_in[16];
    float* out = (float*)d_out;

    _Float16* gbuf = (_Float16*)d_ws;                 // 128 MB inter-layer buffer
    _Float16* wbuf = gbuf + (size_t)67108864;         // fp16 weights (640 KB)

    hipLaunchKernelGGL(convert_w, dim3(1280), dim3(256), 0, stream,
                       Whh0, Wih1, Whh1, Wih2, Whh2, wbuf);
    hipLaunchKernelGGL(lstm3_kernel, dim3(BDIM), dim3(NT), 0, stream,
                       x, Wih0, bih0, bhh0, bih1, bhh1, bih2, bhh2,
                       fc1w, fc1b, fc2w, fc2b, out, gbuf, wbuf);
}

// Round 7
// 3657.684 us; speedup vs baseline: 1.3214x; 1.3214x over previous
//
#include <hip/hip_runtime.h>

#define HDIM 128
#define TDIM 2048
#define BDIM 256
#define CHUNK 16
#define NT 512
#define XGP 20   // fp32 dword pitch per gate row in xg_s

typedef _Float16 half8_t __attribute__((ext_vector_type(8)));
typedef float f32x4 __attribute__((ext_vector_type(4)));

__device__ __forceinline__ f32x4 mfma16(half8_t a, half8_t b, f32x4 c) {
    return __builtin_amdgcn_mfma_f32_16x16x32_f16(a, b, c, 0, 0, 0);
}

// Workgroup barrier WITHOUT the compiler's vmcnt(0) drain: LDS visibility only.
__device__ __forceinline__ void fast_barrier() {
    asm volatile("s_waitcnt lgkmcnt(0)\n\ts_barrier" ::: "memory");
}

__device__ __forceinline__ float sigm_f(float x) { return 1.0f / (1.0f + __expf(-x)); }
__device__ __forceinline__ float tanh_f(float x) { return 1.0f - 2.0f / (1.0f + __expf(2.0f * x)); }

// One-time fp32 -> fp16 weight conversion. Segments of 65536: [Whh0,Wih1,Whh1,Wih2,Whh2]
__global__ __launch_bounds__(256)
void convert_w(const float* __restrict__ Whh0, const float* __restrict__ Wih1,
               const float* __restrict__ Whh1, const float* __restrict__ Wih2,
               const float* __restrict__ Whh2, _Float16* __restrict__ dst) {
    int i = blockIdx.x * 256 + threadIdx.x;
    int seg = i >> 16, off = i & 65535;
    const float* s = (seg == 0) ? Whh0 : (seg == 1) ? Wih1 : (seg == 2) ? Whh1
                   : (seg == 3) ? Wih2 : Whh2;
    dst[i] = (_Float16)s[off];
}

__global__ __launch_bounds__(NT, 2)
void lstm3_kernel(const float* __restrict__ x,   const float* __restrict__ Wih0,
                  const float* __restrict__ bih0, const float* __restrict__ bhh0,
                  const float* __restrict__ bih1, const float* __restrict__ bhh1,
                  const float* __restrict__ bih2, const float* __restrict__ bhh2,
                  const float* __restrict__ fc1w, const float* __restrict__ fc1b,
                  const float* __restrict__ fc2w, const float* __restrict__ fc2b,
                  float* __restrict__ out,
                  _Float16* __restrict__ gbuf, const _Float16* __restrict__ wbuf)
{
    // rolling 16-step h window: row t&15 holds h(t). Doubles as output staging.
    __shared__ __align__(16) _Float16 hwin_s[CHUNK][HDIM];
    __shared__ __align__(16) _Float16 xin_s[2][CHUNK][HDIM];
    __shared__ __align__(16) float xg_s[2][512 * XGP];
    __shared__ __align__(16) float z_s[64];

    const int tid = threadIdx.x;
    const int ln = tid & 63;
    const int wv = tid >> 6;          // wave id 0..7 -> owns units [16wv,16wv+16)
    const int n16 = ln & 15;          // unit-within-wave / MFMA column
    const int kb = (ln >> 4) * 8;     // k-element offset within a 32-block
    const int un = wv * 16 + n16;     // this lane's hidden unit
    const int b = blockIdx.x;

    // ================= layer 0 (in_dim = 1) =================
    {
        float bsum[4], w0[4];
        half8_t bhh[4][4];            // rec B-frags: gate tile tau, K-block kk
#pragma unroll
        for (int tau = 0; tau < 4; ++tau) {
            const int g = tau * HDIM + un;
            bsum[tau] = bih0[g] + bhh0[g];
            w0[tau] = Wih0[g];
#pragma unroll
            for (int kk = 0; kk < 4; ++kk)
                bhh[tau][kk] = *(const half8_t*)(wbuf + (size_t)g * HDIM + kk * 32 + kb);
        }
        if (tid < HDIM) hwin_s[CHUNK - 1][tid] = (_Float16)0.f;
        float c = 0.f;
        float4 xp[4];
        {
            const float4* xq = (const float4*)(x + (size_t)b * TDIM);
#pragma unroll
            for (int i = 0; i < 4; ++i) xp[i] = xq[i];
        }

#pragma unroll 1
        for (int t0 = 0; t0 < TDIM; t0 += CHUNK) {
            float xv[CHUNK];
#pragma unroll
            for (int i = 0; i < 4; ++i) {
                xv[4 * i] = xp[i].x; xv[4 * i + 1] = xp[i].y;
                xv[4 * i + 2] = xp[i].z; xv[4 * i + 3] = xp[i].w;
            }
            int tn = (t0 + CHUNK < TDIM) ? (t0 + CHUNK) : t0;
            const float4* xq = (const float4*)(x + (size_t)b * TDIM + tn);
#pragma unroll
            for (int i = 0; i < 4; ++i) xp[i] = xq[i];

#pragma unroll
            for (int tt = 0; tt < CHUNK; ++tt) {
                fast_barrier();
                const int t = t0 + tt, row = (t + CHUNK - 1) & 15;
                // A-broadcast: every lane loads h[k], all 16 M-rows identical
                half8_t A0 = *(const half8_t*)&hwin_s[row][kb];
                half8_t A1 = *(const half8_t*)&hwin_s[row][32 + kb];
                half8_t A2 = *(const half8_t*)&hwin_s[row][64 + kb];
                half8_t A3 = *(const half8_t*)&hwin_s[row][96 + kb];
                float g4[4];
#pragma unroll
                for (int tau = 0; tau < 4; ++tau) {
                    f32x4 Cz = {0.f, 0.f, 0.f, 0.f};
                    Cz = mfma16(A0, bhh[tau][0], Cz);
                    Cz = mfma16(A1, bhh[tau][1], Cz);
                    Cz = mfma16(A2, bhh[tau][2], Cz);
                    Cz = mfma16(A3, bhh[tau][3], Cz);
                    g4[tau] = Cz[0];   // all rows/regs identical
                }
                float ig = sigm_f(g4[0] + xv[tt] * w0[0] + bsum[0]);
                float fg = sigm_f(g4[1] + xv[tt] * w0[1] + bsum[1]);
                float gg = tanh_f(g4[2] + xv[tt] * w0[2] + bsum[2]);
                float og = sigm_f(g4[3] + xv[tt] * w0[3] + bsum[3]);
                c = fg * c + ig * gg;
                if (kb == 0) hwin_s[t & 15][un] = (_Float16)(og * tanh_f(c));
            }
            fast_barrier();
            int2 v = ((const int2*)&hwin_s[0][0])[tid];
            ((int2*)(gbuf + ((size_t)b * TDIM + t0) * HDIM))[tid] = v;
        }
    }

    // ================= layers 1,2 (MFMA rec + MFMA proj) =================
#pragma unroll 1
    for (int layer = 1; layer < 3; ++layer) {
        const _Float16* whh_p = wbuf + (size_t)((layer == 1) ? 2 : 4) * 65536;
        const _Float16* wih_p = wbuf + (size_t)((layer == 1) ? 1 : 3) * 65536;
        const float* bih = (layer == 1) ? bih1 : bih2;
        const float* bhh = (layer == 1) ? bhh1 : bhh2;

        float bsum[4];
        half8_t bhhf[4][4], bihf[4][4];
#pragma unroll
        for (int tau = 0; tau < 4; ++tau) {
            const int g = tau * HDIM + un;
            bsum[tau] = bih[g] + bhh[g];
#pragma unroll
            for (int kk = 0; kk < 4; ++kk)
                bhhf[tau][kk] = *(const half8_t*)(whh_p + (size_t)g * HDIM + kk * 32 + kb);
            // proj B-frags: wave wv owns gate tiles 4wv..4wv+3 (for the chunk GEMM)
            const int gp = (wv * 4 + tau) * 16 + n16;
#pragma unroll
            for (int kk = 0; kk < 4; ++kk)
                bihf[tau][kk] = *(const half8_t*)(wih_p + (size_t)gp * HDIM + kk * 32 + kb);
        }

        __syncthreads();   // REAL barrier: drains prev layer's gbuf stores before reads
        if (tid < HDIM) hwin_s[CHUNK - 1][tid] = (_Float16)0.f;
        float c = 0.f;

        // ---- prologue: proj chunk 0 -> xg_s[0], prefetch chunk 1 ----
        int2 stage = ((const int2*)(gbuf + (size_t)b * TDIM * HDIM))[tid];
        ((int2*)&xin_s[0][0][0])[tid] = stage;
        __syncthreads();
        {
            half8_t A0 = *(const half8_t*)&xin_s[0][n16][kb];
            half8_t A1 = *(const half8_t*)&xin_s[0][n16][32 + kb];
            half8_t A2 = *(const half8_t*)&xin_s[0][n16][64 + kb];
            half8_t A3 = *(const half8_t*)&xin_s[0][n16][96 + kb];
#pragma unroll
            for (int tau = 0; tau < 4; ++tau) {
                f32x4 a = {0.f, 0.f, 0.f, 0.f};
                a = mfma16(A0, bihf[tau][0], a);
                a = mfma16(A1, bihf[tau][1], a);
                a = mfma16(A2, bihf[tau][2], a);
                a = mfma16(A3, bihf[tau][3], a);
                const int g = (wv * 4 + tau) * 16 + n16;
                *(f32x4*)&xg_s[0][g * XGP + (kb >> 1)] = a;   // (ln>>4)*4 = kb/2
            }
        }
        stage = ((const int2*)(gbuf + ((size_t)b * TDIM + CHUNK) * HDIM))[tid];

        f32x4 pacc[4];
#pragma unroll 1
        for (int t0 = 0; t0 < TDIM; t0 += CHUNK) {
            const int ci = t0 >> 4, rbuf = ci & 1, cb = rbuf ^ 1;
            ((int2*)&xin_s[cb][0][0])[tid] = stage;
            int tn = (t0 + 2 * CHUNK < TDIM) ? (t0 + 2 * CHUNK) : t0;
            stage = ((const int2*)(gbuf + ((size_t)b * TDIM + tn) * HDIM))[tid];

            float2 xgv[4];
#pragma unroll
            for (int tt = 0; tt < CHUNK; ++tt) {
                fast_barrier();
                const int t = t0 + tt, row = (t + CHUNK - 1) & 15;
                half8_t A0 = *(const half8_t*)&hwin_s[row][kb];
                half8_t A1 = *(const half8_t*)&hwin_s[row][32 + kb];
                half8_t A2 = *(const half8_t*)&hwin_s[row][64 + kb];
                half8_t A3 = *(const half8_t*)&hwin_s[row][96 + kb];

                if (tt == 0) {
                    // proj GEMM for chunk ci+1 on the matrix pipe
                    half8_t X0 = *(const half8_t*)&xin_s[cb][n16][kb];
                    half8_t X1 = *(const half8_t*)&xin_s[cb][n16][32 + kb];
                    half8_t X2 = *(const half8_t*)&xin_s[cb][n16][64 + kb];
                    half8_t X3 = *(const half8_t*)&xin_s[cb][n16][96 + kb];
#pragma unroll
                    for (int tau = 0; tau < 4; ++tau) {
                        f32x4 a = {0.f, 0.f, 0.f, 0.f};
                        a = mfma16(X0, bihf[tau][0], a);
                        a = mfma16(X1, bihf[tau][1], a);
                        a = mfma16(X2, bihf[tau][2], a);
                        a = mfma16(X3, bihf[tau][3], a);
                        pacc[tau] = a;
                    }
                }
                if ((tt & 1) == 0) {
#pragma unroll
                    for (int q = 0; q < 4; ++q)
                        xgv[q] = *(const float2*)&xg_s[rbuf][(q * HDIM + un) * XGP + tt];
                }

                float g4[4];
#pragma unroll
                for (int tau = 0; tau < 4; ++tau) {
                    f32x4 Cz = {0.f, 0.f, 0.f, 0.f};
                    Cz = mfma16(A0, bhhf[tau][0], Cz);
                    Cz = mfma16(A1, bhhf[tau][1], Cz);
                    Cz = mfma16(A2, bhhf[tau][2], Cz);
                    Cz = mfma16(A3, bhhf[tau][3], Cz);
                    g4[tau] = Cz[0];
                }

                float x0 = (tt & 1) ? xgv[0].y : xgv[0].x;
                float x1 = (tt & 1) ? xgv[1].y : xgv[1].x;
                float x2 = (tt & 1) ? xgv[2].y : xgv[2].x;
                float x3 = (tt & 1) ? xgv[3].y : xgv[3].x;
                float ig = sigm_f(g4[0] + x0 + bsum[0]);
                float fg = sigm_f(g4[1] + x1 + bsum[1]);
                float gg = tanh_f(g4[2] + x2 + bsum[2]);
                float og = sigm_f(g4[3] + x3 + bsum[3]);
                c = fg * c + ig * gg;
                if (kb == 0) hwin_s[t & 15][un] = (_Float16)(og * tanh_f(c));

                if (tt == CHUNK - 1) {
#pragma unroll
                    for (int tau = 0; tau < 4; ++tau) {
                        const int g = (wv * 4 + tau) * 16 + n16;
                        *(f32x4*)&xg_s[cb][g * XGP + (kb >> 1)] = pacc[tau];
                    }
                }
            }
            if (layer == 1) {
                fast_barrier();
                int2 v = ((const int2*)&hwin_s[0][0])[tid];
                ((int2*)(gbuf + ((size_t)b * TDIM + t0) * HDIM))[tid] = v;
            }
        }
    }

    // ---- FC head: final h (t=2047) is hwin_s[15] ----
    __syncthreads();
    if (tid < 64) {
        const float* w = fc1w + tid * HDIM;
        float s = fc1b[tid];
#pragma unroll
        for (int k = 0; k < HDIM; ++k) s += w[k] * (float)hwin_s[CHUNK - 1][k];
        z_s[tid] = fmaxf(s, 0.0f);
    }
    __syncthreads();
    if (tid < 5) {
        const float* w = fc2w + tid * 64;
        float s = fc2b[tid];
#pragma unroll
        for (int k = 0; k < 64; ++k) s += w[k] * z_s[k];
        out[b * 5 + tid] = s;
    }
}

extern "C" void kernel_launch(void* const* d_in, const int* in_sizes, int n_in,
                              void* d_out, int out_size, void* d_ws, size_t ws_size,
                              hipStream_t stream) {
    (void)in_sizes; (void)n_in; (void)out_size; (void)ws_size;
    const float* x    = (const float*)d_in[0];
    const float* Wih0 = (const float*)d_in[1];
    const float* Whh0 = (const float*)d_in[2];
    const float* bih0 = (const float*)d_in[3];
    const float* bhh0 = (const float*)d_in[4];
    const float* Wih1 = (const float*)d_in[5];
    const float* Whh1 = (const float*)d_in[6];
    const float* bih1 = (const float*)d_in[7];
    const float* bhh1 = (const float*)d_in[8];
    const float* Wih2 = (const float*)d_in[9];
    const float* Whh2 = (const float*)d_in[10];
    const float* bih2 = (const float*)d_in[11];
    const float* bhh2 = (const float*)d_in[12];
    const float* fc1w = (const float*)d_in[13];
    const float* fc1b = (const float*)d_in[14];
    const float* fc2w = (const float*)d_in[15];
    const float* fc2b = (const float*)d_in[16];
    float* out = (float*)d_out;

    _Float16* gbuf = (_Float16*)d_ws;                 // 128 MB inter-layer buffer
    _Float16* wbuf = gbuf + (size_t)67108864;         // fp16 weights (640 KB)

    hipLaunchKernelGGL(convert_w, dim3(1280), dim3(256), 0, stream,
                       Whh0, Wih1, Whh1, Wih2, Whh2, wbuf);
    hipLaunchKernelGGL(lstm3_kernel, dim3(BDIM), dim3(NT), 0, stream,
                       x, Wih0, bih0, bhh0, bih1, bhh1, bih2, bhh2,
                       fc1w, fc1b, fc2w, fc2b, out, gbuf, wbuf);
}